// Round 2
// baseline (339.959 us; speedup 1.0000x reference)
//
#include <hip/hip_runtime.h>
#include <hip/hip_bf16.h>
#include <stdint.h>

#define DEVINL __device__ __forceinline__

typedef unsigned short u16;
typedef unsigned int u32;
typedef __attribute__((ext_vector_type(8))) __bf16 bf16x8;
typedef __attribute__((ext_vector_type(4))) float f32x4;
typedef __attribute__((ext_vector_type(16))) float f32x16;

static constexpr int NQ = 2048, MC = 512, DIMC = 1024, LTOT = 2560;
static constexpr float EPS = 1e-6f;

DEVINL u16 f2bf(float f) {
  u32 u = __float_as_uint(f);
  u32 r = (u + 0x7FFFu + ((u >> 16) & 1u)) >> 16;
  return (u16)r;
}
DEVINL float bf2f(u16 h) { return __uint_as_float(((u32)h) << 16); }

DEVINL void gload16(const void* g, void* l) {
  __builtin_amdgcn_global_load_lds((const __attribute__((address_space(1))) void*)g,
                                   (__attribute__((address_space(3))) void*)l, 16, 0, 0);
}

// ---------------- fp32 -> bf16 convert ----------------
__global__ void cvt_bf16(const float* __restrict__ src, u16* __restrict__ dst) {
  size_t i = ((size_t)blockIdx.x * 256 + threadIdx.x) * 8;
  float4 a = *(const float4*)(src + i);
  float4 b = *(const float4*)(src + i + 4);
  union { uint4 u; u16 s[8]; } o;
  o.s[0] = f2bf(a.x); o.s[1] = f2bf(a.y); o.s[2] = f2bf(a.z); o.s[3] = f2bf(a.w);
  o.s[4] = f2bf(b.x); o.s[5] = f2bf(b.y); o.s[6] = f2bf(b.z); o.s[7] = f2bf(b.w);
  *(uint4*)(dst + i) = o.u;
}

// ---------------- C = A @ B^T  (A:[M,K] bf16, B:[N,K] bf16) ----------------
template <int M, int N, int K, bool OUT_BF16, bool HAS_BIAS>
__launch_bounds__(256, 2)
__global__ void gemm_bt(const u16* __restrict__ A, const u16* __restrict__ Bw,
                        void* __restrict__ Cout, const float* __restrict__ bias) {
  __shared__ u16 la[128 * 64];
  __shared__ u16 lb[128 * 64];
  const int tid = threadIdx.x;
  const int lane = tid & 63, wid = tid >> 6;
  const int tm = blockIdx.x / (N / 128), tn = blockIdx.x % (N / 128);
  const int m0 = tm * 128, n0 = tn * 128;
  const int wm = (wid >> 1) * 64, wn = (wid & 1) * 64;
  const int srow = lane >> 3, scol = (lane & 7) * 8;
  const int cn = lane & 15, rg = lane >> 4;

  f32x4 acc[4][4] = {};

  for (int kt = 0; kt < K; kt += 64) {
    __syncthreads();
#pragma unroll
    for (int c = 0; c < 4; ++c) {
      int s = c * 4 + wid;
      gload16(A + (size_t)(m0 + s * 8 + srow) * K + kt + scol, &la[s * 512]);
      gload16(Bw + (size_t)(n0 + s * 8 + srow) * K + kt + scol, &lb[s * 512]);
    }
    __syncthreads();
#pragma unroll
    for (int kk = 0; kk < 2; ++kk) {
      bf16x8 af[4], bfr[4];
      const int ko = kk * 32 + rg * 8;
#pragma unroll
      for (int mi = 0; mi < 4; ++mi) af[mi] = *(const bf16x8*)&la[(wm + mi * 16 + cn) * 64 + ko];
#pragma unroll
      for (int ni = 0; ni < 4; ++ni) bfr[ni] = *(const bf16x8*)&lb[(wn + ni * 16 + cn) * 64 + ko];
#pragma unroll
      for (int mi = 0; mi < 4; ++mi)
#pragma unroll
        for (int ni = 0; ni < 4; ++ni)
          acc[mi][ni] = __builtin_amdgcn_mfma_f32_16x16x32_bf16(af[mi], bfr[ni], acc[mi][ni], 0, 0, 0);
    }
  }
#pragma unroll
  for (int mi = 0; mi < 4; ++mi)
#pragma unroll
    for (int ni = 0; ni < 4; ++ni) {
      const int col = n0 + wn + ni * 16 + cn;
      const float bv = HAS_BIAS ? bias[col] : 0.0f;
#pragma unroll
      for (int r = 0; r < 4; ++r) {
        const int row = m0 + wm + mi * 16 + rg * 4 + r;
        const float v = acc[mi][ni][r] + bv;
        if (OUT_BF16) ((u16*)Cout)[(size_t)row * N + col] = f2bf(v);
        else          ((float*)Cout)[(size_t)row * N + col] = v;
      }
    }
}

// ---------------- K rmsnorm + V transpose into attention layouts ----------------
__global__ void reorg_kv(const u16* __restrict__ qkvx, const u16* __restrict__ kvy,
                         const float* __restrict__ knw,
                         u16* __restrict__ kb, u16* __restrict__ vtb) {
  const int tid = threadIdx.x;
  const int bh = blockIdx.x / 40, t = blockIdx.x % 40;
  const int b = bh >> 4, h = bh & 15;
  const u16* src; int stride, kcol, vcol, l0, srow0;
  if (t < 32) {
    src = qkvx; stride = 3 * DIMC; kcol = DIMC + h * 64; vcol = 2 * DIMC + h * 64;
    srow0 = b * NQ + t * 64; l0 = t * 64;
  } else {
    src = kvy; stride = 2 * DIMC; kcol = h * 64; vcol = DIMC + h * 64;
    srow0 = b * MC + (t - 32) * 64; l0 = NQ + (t - 32) * 64;
  }
  {  // K with rmsnorm: thread -> token i, 16 dims
    const int i = tid >> 2, d0 = (tid & 3) * 16;
    const u16* p = src + (size_t)(srow0 + i) * stride + kcol + d0;
    uint4 r0 = *(const uint4*)(p);
    uint4 r1 = *(const uint4*)(p + 8);
    const u16* s0 = (const u16*)&r0; const u16* s1 = (const u16*)&r1;
    float f[16]; float ss = 0.f;
#pragma unroll
    for (int j = 0; j < 8; ++j) { f[j] = bf2f(s0[j]); ss += f[j] * f[j]; }
#pragma unroll
    for (int j = 0; j < 8; ++j) { f[8 + j] = bf2f(s1[j]); ss += f[8 + j] * f[8 + j]; }
    ss += __shfl_xor(ss, 1); ss += __shfl_xor(ss, 2);
    const float rs = rsqrtf(ss * (1.0f / 64.0f) + EPS);
    union { uint4 u; u16 s[8]; } o0, o1;
#pragma unroll
    for (int j = 0; j < 8; ++j) o0.s[j] = f2bf(f[j] * rs * knw[d0 + j]);
#pragma unroll
    for (int j = 0; j < 8; ++j) o1.s[j] = f2bf(f[8 + j] * rs * knw[d0 + 8 + j]);
    u16* q = kb + ((size_t)bh * LTOT + l0 + i) * 64 + d0;
    *(uint4*)q = o0.u;
    *(uint4*)(q + 8) = o1.u;
  }
  {  // V transpose: thread -> dim d, 16 tokens
    const int d = tid >> 2, g = tid & 3;
    const u16* p = src + (size_t)srow0 * stride + vcol + d;
    u16 buf[16];
#pragma unroll
    for (int j = 0; j < 16; ++j) buf[j] = p[(size_t)(g * 16 + j) * stride];
    u16* q = vtb + ((size_t)bh * 64 + d) * LTOT + l0 + g * 16;
    *(uint4*)q = *(uint4*)&buf[0];
    *(uint4*)(q + 8) = *(uint4*)&buf[8];
  }
}

// ---------------- flash attention, swapped-QK^T 32x32x16, no LDS ----------------
// grid: 512 blocks = 32 bh * 16 q-tiles, 4 waves * 32 q-rows = 128 q/block.
__launch_bounds__(256, 2)
__global__ void attn_fwd(const u16* __restrict__ qkvx, const u16* __restrict__ kb,
                         const u16* __restrict__ vtb, const float* __restrict__ qnw,
                         u16* __restrict__ attnb) {
  const int tid = threadIdx.x;
  const int lane = tid & 63, wid = tid >> 6;
  const int hi = lane >> 5, ln32 = lane & 31;
  // XCD-aware bijective swizzle (512 = 8*64)
  const int swz = (blockIdx.x & 7) * 64 + (blockIdx.x >> 3);
  const int qt = swz & 15, bh = swz >> 4;
  const int b = bh >> 4, h = bh & 15;
  const int qrow = qt * 128 + wid * 32 + ln32;

  union U4 { uint4 u; bf16x8 v; };

  // ---- Q load + rmsnorm (scale 1/8 and log2e folded in) ----
  bf16x8 qb[4];
  {
    const u16* qp = qkvx + (size_t)(b * NQ + qrow) * (3 * DIMC) + h * 64 + hi * 8;
    uint4 qr4[4];
#pragma unroll
    for (int s = 0; s < 4; ++s) qr4[s] = *(const uint4*)(qp + s * 16);
    float f[32]; float ss = 0.f;
#pragma unroll
    for (int s = 0; s < 4; ++s) {
      const u16* e = (const u16*)&qr4[s];
#pragma unroll
      for (int j = 0; j < 8; ++j) { float v = bf2f(e[j]); f[s * 8 + j] = v; ss += v * v; }
    }
    ss += __shfl_xor(ss, 32);
    const float rs = rsqrtf(ss * (1.0f / 64.0f) + EPS) * 0.125f * 1.44269504088896f;
#pragma unroll
    for (int s = 0; s < 4; ++s) {
      union { u16 s16[8]; bf16x8 v; } o;
#pragma unroll
      for (int j = 0; j < 8; ++j) o.s16[j] = f2bf(f[s * 8 + j] * rs * qnw[s * 16 + hi * 8 + j]);
      qb[s] = o.v;
    }
  }

  const u16* kptr = kb + (size_t)bh * LTOT * 64 + (size_t)ln32 * 64 + hi * 8;
  const u16* vptr0 = vtb + (size_t)bh * 64 * LTOT + (size_t)ln32 * LTOT + hi * 8;
  const u16* vptr1 = vptr0 + (size_t)32 * LTOT;

  // prologue: K frags for tile 0 (A-operand: row=key=ln32, k=d at hi*8 + 16s)
  U4 kf[4];
#pragma unroll
  for (int s = 0; s < 4; ++s) kf[s].u = *(const uint4*)(kptr + s * 16);
  kptr += 32 * 64;

  float m_run = -1e30f, l_run = 0.f;
  f32x16 acc0 = {}, acc1 = {};

#pragma unroll 2
  for (int t = 0; t < LTOT / 32; ++t) {
    // V frags for tile t (B-operand: col=d=ln32(+32), k=key at hi*8 + 16ks)
    U4 vf[4];
#pragma unroll
    for (int ks = 0; ks < 2; ++ks) {
      vf[ks].u     = *(const uint4*)(vptr0 + ks * 16);
      vf[2 + ks].u = *(const uint4*)(vptr1 + ks * 16);
    }
    vptr0 += 32; vptr1 += 32;

    // S^T[key][q] = K @ Q^T  (lane: q=ln32, 16 keys in regs)
    f32x16 sa = {};
#pragma unroll
    for (int s = 0; s < 4; ++s)
      sa = __builtin_amdgcn_mfma_f32_32x32x16_bf16(kf[s].v, qb[s], sa, 0, 0, 0);

    // prefetch K frags for tile t+1 (reads 1 tile past end on last iter: in-ws, unused)
    U4 kn[4];
#pragma unroll
    for (int s = 0; s < 4; ++s) kn[s].u = *(const uint4*)(kptr + s * 16);
    kptr += 32 * 64;

    // ---- in-lane online softmax (log2 domain), defer-max THR=8 ----
    float mx = sa[0];
#pragma unroll
    for (int r = 1; r < 16; ++r) mx = fmaxf(mx, sa[r]);
    mx = fmaxf(mx, __shfl_xor(mx, 32));
    if (__any(mx > m_run + 8.0f)) {
      const float mn = fmaxf(m_run, mx);
      const float corr = exp2f(m_run - mn);
      m_run = mn;
      l_run *= corr;
#pragma unroll
      for (int r = 0; r < 16; ++r) {
        const int qr = (r & 3) + 8 * (r >> 2) + 4 * hi;
        const float c = __shfl(corr, qr);
        acc0[r] *= c; acc1[r] *= c;
      }
    }
    float p[16]; float sum = 0.f;
#pragma unroll
    for (int r = 0; r < 16; ++r) { p[r] = exp2f(sa[r] - m_run); sum += p[r]; }
    sum += __shfl_xor(sum, 32);
    l_run += sum;

    // ---- pack P -> bf16 A-frags: words w[j] = keys {4hi+2j, 4hi+2j+1} per 8-key group
    u32 w[8];
#pragma unroll
    for (int j = 0; j < 8; ++j) {
      __hip_bfloat162 h2 = __float22bfloat162_rn(make_float2(p[2 * j], p[2 * j + 1]));
      w[j] = *(u32*)&h2;
    }
    // exchange halves so A-frag words are key-ascending: pairs (w0,w2),(w1,w3),(w4,w6),(w5,w7)
    union { u32 w4[4]; bf16x8 v; } pa0, pa1;
#pragma unroll
    for (int g = 0; g < 2; ++g)
#pragma unroll
      for (int j = 0; j < 2; ++j) {
        const u32 a = w[4 * g + j], c = w[4 * g + j + 2];
        const u32 xa = __shfl_xor(a, 32), xc = __shfl_xor(c, 32);
        u32 lo_w = hi ? xc : a;
        u32 hi_w = hi ? c : xa;
        if (g == 0) { pa0.w4[j] = lo_w; pa0.w4[j + 2] = hi_w; }
        else        { pa1.w4[j] = lo_w; pa1.w4[j + 2] = hi_w; }
      }

    // ---- O += P @ V ----
    acc0 = __builtin_amdgcn_mfma_f32_32x32x16_bf16(pa0.v, vf[0].v, acc0, 0, 0, 0);
    acc0 = __builtin_amdgcn_mfma_f32_32x32x16_bf16(pa1.v, vf[1].v, acc0, 0, 0, 0);
    acc1 = __builtin_amdgcn_mfma_f32_32x32x16_bf16(pa0.v, vf[2].v, acc1, 0, 0, 0);
    acc1 = __builtin_amdgcn_mfma_f32_32x32x16_bf16(pa1.v, vf[3].v, acc1, 0, 0, 0);

#pragma unroll
    for (int s = 0; s < 4; ++s) kf[s] = kn[s];
  }

  // ---- epilogue: divide by l (broadcast per C-row) and store ----
  const float rinv = 1.0f / l_run;
  const size_t obase = (size_t)(b * NQ + qt * 128 + wid * 32) * DIMC + h * 64 + ln32;
#pragma unroll
  for (int r = 0; r < 16; ++r) {
    const int qr = (r & 3) + 8 * (r >> 2) + 4 * hi;
    const float ri = __shfl(rinv, qr);
    u16* op = attnb + obase + (size_t)qr * DIMC;
    op[0]  = f2bf(acc0[r] * ri);
    op[32] = f2bf(acc1[r] * ri);
  }
}

extern "C" void kernel_launch(void* const* d_in, const int* in_sizes, int n_in,
                              void* d_out, int out_size, void* d_ws, size_t ws_size,
                              hipStream_t stream) {
  const float* x      = (const float*)d_in[0];
  const float* ctx    = (const float*)d_in[1];
  const float* qkv_w  = (const float*)d_in[2];
  const float* kv_y_w = (const float*)d_in[3];
  const float* proj_w = (const float*)d_in[4];
  const float* proj_b = (const float*)d_in[5];
  const float* q_norm_w = (const float*)d_in[6];
  const float* k_norm_w = (const float*)d_in[7];
  float* out = (float*)d_out;

  char* ws = (char*)d_ws;
  u16* xb    = (u16*)(ws);                // 4096*1024      (8.0 MB)
  u16* cb    = (u16*)(ws + 8388608);      // 1024*1024      (2.0 MB)
  u16* wqkv  = (u16*)(ws + 10485760);     // 3072*1024      (6.0 MB)
  u16* wkv   = (u16*)(ws + 16777216);     // 2048*1024      (4.0 MB)
  u16* wproj = (u16*)(ws + 20971520);     // 1024*1024      (2.0 MB)
  u16* qkvx  = (u16*)(ws + 23068672);     // 4096*3072      (24 MB)
  u16* kvy   = (u16*)(ws + 48234496);     // 1024*2048      (4.0 MB)
  u16* kbuf  = (u16*)(ws + 52428800);     // 32*2560*64     (10 MB)
  u16* vtb   = (u16*)(ws + 62914560);     // 32*64*2560     (10 MB)
  u16* attnb = (u16*)(ws + 73400320);     // 4096*1024      (8.0 MB)

  cvt_bf16<<<2048, 256, 0, stream>>>(x, xb);
  cvt_bf16<<<512, 256, 0, stream>>>(ctx, cb);
  cvt_bf16<<<1536, 256, 0, stream>>>(qkv_w, wqkv);
  cvt_bf16<<<1024, 256, 0, stream>>>(kv_y_w, wkv);
  cvt_bf16<<<512, 256, 0, stream>>>(proj_w, wproj);

  gemm_bt<4096, 3072, 1024, true, false><<<32 * 24, 256, 0, stream>>>(xb, wqkv, qkvx, nullptr);
  gemm_bt<1024, 2048, 1024, true, false><<<8 * 16, 256, 0, stream>>>(cb, wkv, kvy, nullptr);
  reorg_kv<<<32 * 40, 256, 0, stream>>>(qkvx, kvy, k_norm_w, kbuf, vtb);
  attn_fwd<<<512, 256, 0, stream>>>(qkvx, kbuf, vtb, q_norm_w, attnb);
  gemm_bt<4096, 1024, 1024, false, true><<<32 * 8, 256, 0, stream>>>(attnb, wproj, out, proj_b);
}

// Round 3
// 271.361 us; speedup vs baseline: 1.2528x; 1.2528x over previous
//
#include <hip/hip_runtime.h>
#include <hip/hip_bf16.h>
#include <stdint.h>

#define DEVINL __device__ __forceinline__

typedef unsigned short u16;
typedef unsigned int u32;
typedef __attribute__((ext_vector_type(8))) __bf16 bf16x8;
typedef __attribute__((ext_vector_type(4))) float f32x4;
typedef __attribute__((ext_vector_type(16))) float f32x16;

static constexpr int NQ = 2048, MC = 512, DIMC = 1024, LTOT = 2560;
static constexpr float EPS = 1e-6f;

DEVINL u16 f2bf(float f) {
  u32 u = __float_as_uint(f);
  u32 r = (u + 0x7FFFu + ((u >> 16) & 1u)) >> 16;
  return (u16)r;
}
DEVINL float bf2f(u16 h) { return __uint_as_float(((u32)h) << 16); }

DEVINL void gload16(const void* g, void* l) {
  __builtin_amdgcn_global_load_lds((const __attribute__((address_space(1))) void*)g,
                                   (__attribute__((address_space(3))) void*)l, 16, 0, 0);
}

// ---------------- fused fp32 -> bf16 convert (all 5 tensors) ----------------
__global__ void cvt_all(const float* __restrict__ x, const float* __restrict__ ctx,
                        const float* __restrict__ w1, const float* __restrict__ w2,
                        const float* __restrict__ w3,
                        u16* __restrict__ xb, u16* __restrict__ cb, u16* __restrict__ wq,
                        u16* __restrict__ wk, u16* __restrict__ wp) {
  const int bk = blockIdx.x;
  const float* src; u16* dst; int lb;
  if (bk < 2048)      { src = x;   dst = xb; lb = bk; }
  else if (bk < 2560) { src = ctx; dst = cb; lb = bk - 2048; }
  else if (bk < 4096) { src = w1;  dst = wq; lb = bk - 2560; }
  else if (bk < 5120) { src = w2;  dst = wk; lb = bk - 4096; }
  else                { src = w3;  dst = wp; lb = bk - 5120; }
  size_t i = ((size_t)lb * 256 + threadIdx.x) * 8;
  float4 a = *(const float4*)(src + i);
  float4 b = *(const float4*)(src + i + 4);
  union { uint4 u; u16 s[8]; } o;
  o.s[0] = f2bf(a.x); o.s[1] = f2bf(a.y); o.s[2] = f2bf(a.z); o.s[3] = f2bf(a.w);
  o.s[4] = f2bf(b.x); o.s[5] = f2bf(b.y); o.s[6] = f2bf(b.z); o.s[7] = f2bf(b.w);
  *(uint4*)(dst + i) = o.u;
}

// ---------------- C = A @ B^T  (A:[M,K] bf16, B:[N,K] bf16) ----------------
template <int M, int N, int K, bool OUT_BF16, bool HAS_BIAS>
__launch_bounds__(256, 2)
__global__ void gemm_bt(const u16* __restrict__ A, const u16* __restrict__ Bw,
                        void* __restrict__ Cout, const float* __restrict__ bias) {
  __shared__ u16 la[128 * 64];
  __shared__ u16 lb[128 * 64];
  const int tid = threadIdx.x;
  const int lane = tid & 63, wid = tid >> 6;
  const int tm = blockIdx.x / (N / 128), tn = blockIdx.x % (N / 128);
  const int m0 = tm * 128, n0 = tn * 128;
  const int wm = (wid >> 1) * 64, wn = (wid & 1) * 64;
  const int srow = lane >> 3, scol = (lane & 7) * 8;
  const int cn = lane & 15, rg = lane >> 4;

  f32x4 acc[4][4] = {};

  for (int kt = 0; kt < K; kt += 64) {
    __syncthreads();
#pragma unroll
    for (int c = 0; c < 4; ++c) {
      int s = c * 4 + wid;
      gload16(A + (size_t)(m0 + s * 8 + srow) * K + kt + scol, &la[s * 512]);
      gload16(Bw + (size_t)(n0 + s * 8 + srow) * K + kt + scol, &lb[s * 512]);
    }
    __syncthreads();
#pragma unroll
    for (int kk = 0; kk < 2; ++kk) {
      bf16x8 af[4], bfr[4];
      const int ko = kk * 32 + rg * 8;
#pragma unroll
      for (int mi = 0; mi < 4; ++mi) af[mi] = *(const bf16x8*)&la[(wm + mi * 16 + cn) * 64 + ko];
#pragma unroll
      for (int ni = 0; ni < 4; ++ni) bfr[ni] = *(const bf16x8*)&lb[(wn + ni * 16 + cn) * 64 + ko];
#pragma unroll
      for (int mi = 0; mi < 4; ++mi)
#pragma unroll
        for (int ni = 0; ni < 4; ++ni)
          acc[mi][ni] = __builtin_amdgcn_mfma_f32_16x16x32_bf16(af[mi], bfr[ni], acc[mi][ni], 0, 0, 0);
    }
  }
#pragma unroll
  for (int mi = 0; mi < 4; ++mi)
#pragma unroll
    for (int ni = 0; ni < 4; ++ni) {
      const int col = n0 + wn + ni * 16 + cn;
      const float bv = HAS_BIAS ? bias[col] : 0.0f;
#pragma unroll
      for (int r = 0; r < 4; ++r) {
        const int row = m0 + wm + mi * 16 + rg * 4 + r;
        const float v = acc[mi][ni][r] + bv;
        if (OUT_BF16) ((u16*)Cout)[(size_t)row * N + col] = f2bf(v);
        else          ((float*)Cout)[(size_t)row * N + col] = v;
      }
    }
}

// ---------------- K rmsnorm + frag-major repack of K and V ----------------
// kfb/vfb: [bh][80 tiles][4 frags][64 lanes][8 u16]  (each frag-load = coalesced 1KB)
// K frag s, lane l = K_norm[key=t*32+(l&31)][d = s*16 + (l>>5)*8 .. +8]
// V frag vi, lane l = V[key=t*32+(vi&1)*16+(l>>5)*8 .. +8][d = (vi>>1)*32 + (l&31)]
__global__ void reorg_kv(const u16* __restrict__ qkvx, const u16* __restrict__ kvy,
                         const float* __restrict__ knw,
                         u16* __restrict__ kfb, u16* __restrict__ vfb) {
  __shared__ u16 lk[64 * 72];
  const int tid = threadIdx.x;
  const int bh = blockIdx.x / 40, g = blockIdx.x % 40;
  const int b = bh >> 4, h = bh & 15;
  const u16* src; int stride, kcol, vcol, srow0;
  if (g < 32) {
    src = qkvx; stride = 3 * DIMC; kcol = DIMC + h * 64; vcol = 2 * DIMC + h * 64;
    srow0 = b * NQ + g * 64;
  } else {
    src = kvy; stride = 2 * DIMC; kcol = h * 64; vcol = DIMC + h * 64;
    srow0 = b * MC + (g - 32) * 64;
  }
  {  // Phase A: K rmsnorm -> LDS (row i, 16 dims per thread)
    const int i = tid >> 2, d0 = (tid & 3) * 16;
    const u16* p = src + (size_t)(srow0 + i) * stride + kcol + d0;
    uint4 r0 = *(const uint4*)(p);
    uint4 r1 = *(const uint4*)(p + 8);
    const u16* s0 = (const u16*)&r0; const u16* s1 = (const u16*)&r1;
    float f[16]; float ss = 0.f;
#pragma unroll
    for (int j = 0; j < 8; ++j) { f[j] = bf2f(s0[j]); ss += f[j] * f[j]; }
#pragma unroll
    for (int j = 0; j < 8; ++j) { f[8 + j] = bf2f(s1[j]); ss += f[8 + j] * f[8 + j]; }
    ss += __shfl_xor(ss, 1); ss += __shfl_xor(ss, 2);
    const float rs = rsqrtf(ss * (1.0f / 64.0f) + EPS);
    union { uint4 u; u16 s[8]; } o0, o1;
#pragma unroll
    for (int j = 0; j < 8; ++j) o0.s[j] = f2bf(f[j] * rs * knw[d0 + j]);
#pragma unroll
    for (int j = 0; j < 8; ++j) o1.s[j] = f2bf(f[8 + j] * rs * knw[d0 + 8 + j]);
    *(uint4*)&lk[i * 72 + d0] = o0.u;
    *(uint4*)&lk[i * 72 + d0 + 8] = o1.u;
  }
  __syncthreads();
  // Phase B: frag pack (2 chunks per thread: K from LDS, V gathered from global)
#pragma unroll
  for (int c0 = 0; c0 < 512; c0 += 256) {
    const int c = c0 + tid;
    const int l = c & 63, s = (c >> 6) & 3, tt = c >> 8;
    const int ln32 = l & 31, hi = l >> 5;
    const size_t tbase = ((size_t)bh * 80 + g * 2 + tt) * 2048;
    // K from LDS
    uint4 kv4 = *(const uint4*)&lk[(tt * 32 + ln32) * 72 + s * 16 + hi * 8];
    *(uint4*)(kfb + tbase + s * 512 + l * 8) = kv4;
    // V gather (8 rows x 1 col each lane; lanes span 32 contiguous cols)
    const int key = tt * 32 + (s & 1) * 16 + hi * 8;
    const int d = (s >> 1) * 32 + ln32;
    const u16* vp = src + (size_t)(srow0 + key) * stride + vcol + d;
    union { uint4 u; u16 e[8]; } t;
#pragma unroll
    for (int j = 0; j < 8; ++j) t.e[j] = vp[(size_t)j * stride];
    *(uint4*)(vfb + tbase + s * 512 + l * 8) = t.u;
  }
}

// ---------------- flash attention, swapped-QK^T 32x32x16, split-L ----------------
// grid: 1024 = 32 bh * 16 qt * 2 splits; 4 waves * 32 q-rows.
// Writes normalized partial O (bf16) + per-row (m,l) for the combine kernel.
__launch_bounds__(256, 4)
__global__ void attn_fwd(const u16* __restrict__ qkvx, const u16* __restrict__ kfb,
                         const u16* __restrict__ vfb, const float* __restrict__ qnw,
                         u16* __restrict__ pacc, float* __restrict__ mlb) {
  const int tid = threadIdx.x;
  const int lane = tid & 63, wid = tid >> 6;
  const int hi = lane >> 5, ln32 = lane & 31;
  // XCD-aware bijective swizzle; blocks of one bh stay on one XCD
  const int swz = (blockIdx.x & 7) * 128 + (blockIdx.x >> 3);
  const int sp = swz & 1, qt = (swz >> 1) & 15, bh = swz >> 5;
  const int b = bh >> 4, h = bh & 15;
  const int qrow = qt * 128 + wid * 32 + ln32;

  union U4 { uint4 u; bf16x8 v; };

  // ---- Q load + rmsnorm (scale 1/8 and log2e folded in) ----
  bf16x8 qb[4];
  {
    const u16* qp = qkvx + (size_t)(b * NQ + qrow) * (3 * DIMC) + h * 64 + hi * 8;
    uint4 qr4[4];
#pragma unroll
    for (int s = 0; s < 4; ++s) qr4[s] = *(const uint4*)(qp + s * 16);
    float f[32]; float ss = 0.f;
#pragma unroll
    for (int s = 0; s < 4; ++s) {
      const u16* e = (const u16*)&qr4[s];
#pragma unroll
      for (int j = 0; j < 8; ++j) { float v = bf2f(e[j]); f[s * 8 + j] = v; ss += v * v; }
    }
    ss += __shfl_xor(ss, 32);
    const float rs = rsqrtf(ss * (1.0f / 64.0f) + EPS) * 0.125f * 1.44269504088896f;
#pragma unroll
    for (int s = 0; s < 4; ++s) {
      union { u16 s16[8]; bf16x8 v; } o;
#pragma unroll
      for (int j = 0; j < 8; ++j) o.s16[j] = f2bf(f[s * 8 + j] * rs * qnw[s * 16 + hi * 8 + j]);
      qb[s] = o.v;
    }
  }

  // frag-major bases: per tile 2048 u16 (4 frags x 64 lanes x 8)
  const u16* kbase = kfb + ((size_t)bh * 80 + sp * 40) * 2048 + lane * 8;
  const u16* vbase = vfb + ((size_t)bh * 80 + sp * 40) * 2048 + lane * 8;

  U4 kf[4];
#pragma unroll
  for (int s = 0; s < 4; ++s) kf[s].u = *(const uint4*)(kbase + s * 512);

  float m_run = -1e30f, l_run = 0.f;
  f32x16 acc0 = {}, acc1 = {};

#pragma unroll 2
  for (int t = 0; t < 40; ++t) {
    // V frags for tile t (coalesced 1KB loads)
    const u16* vt = vbase + (size_t)t * 2048;
    U4 vf[4];
#pragma unroll
    for (int vi = 0; vi < 4; ++vi) vf[vi].u = *(const uint4*)(vt + vi * 512);

    // S^T[key][q] = K @ Q^T  (lane: q=ln32, 16 keys in regs)
    f32x16 sa = {};
#pragma unroll
    for (int s = 0; s < 4; ++s)
      sa = __builtin_amdgcn_mfma_f32_32x32x16_bf16(kf[s].v, qb[s], sa, 0, 0, 0);

    // prefetch K frags for tile t+1 (past-end read stays inside ws, unused)
    const u16* kt = kbase + (size_t)(t + 1) * 2048;
    U4 kn[4];
#pragma unroll
    for (int s = 0; s < 4; ++s) kn[s].u = *(const uint4*)(kt + s * 512);

    // ---- in-lane online softmax (log2 domain), defer-max THR=8, tree reduces ----
    float t8[8];
#pragma unroll
    for (int j = 0; j < 8; ++j) t8[j] = fmaxf(sa[j], sa[j + 8]);
    float t4m[4];
#pragma unroll
    for (int j = 0; j < 4; ++j) t4m[j] = fmaxf(t8[j], t8[j + 4]);
    float mx = fmaxf(fmaxf(t4m[0], t4m[2]), fmaxf(t4m[1], t4m[3]));
    mx = fmaxf(mx, __shfl_xor(mx, 32));
    if (__any(mx > m_run + 8.0f)) {
      const float mn = fmaxf(m_run, mx);
      const float corr = exp2f(m_run - mn);
      m_run = mn;
      l_run *= corr;
#pragma unroll
      for (int r = 0; r < 16; ++r) {
        const int qr = (r & 3) + 8 * (r >> 2) + 4 * hi;
        const float c = __shfl(corr, qr);
        acc0[r] *= c; acc1[r] *= c;
      }
    }
    float p[16];
#pragma unroll
    for (int r = 0; r < 16; ++r) p[r] = exp2f(sa[r] - m_run);
    float s8[8];
#pragma unroll
    for (int j = 0; j < 8; ++j) s8[j] = p[j] + p[j + 8];
    float s4[4];
#pragma unroll
    for (int j = 0; j < 4; ++j) s4[j] = s8[j] + s8[j + 4];
    float sum = (s4[0] + s4[2]) + (s4[1] + s4[3]);
    sum += __shfl_xor(sum, 32);
    l_run += sum;

    // ---- pack P -> bf16 A-frags ----
    u32 w[8];
#pragma unroll
    for (int j = 0; j < 8; ++j) {
      __hip_bfloat162 h2 = __float22bfloat162_rn(make_float2(p[2 * j], p[2 * j + 1]));
      w[j] = *(u32*)&h2;
    }
    union { u32 w4[4]; bf16x8 v; } pa0, pa1;
#pragma unroll
    for (int g = 0; g < 2; ++g)
#pragma unroll
      for (int j = 0; j < 2; ++j) {
        const u32 a = w[4 * g + j], c = w[4 * g + j + 2];
        const u32 xa = __shfl_xor(a, 32), xc = __shfl_xor(c, 32);
        u32 lo_w = hi ? xc : a;
        u32 hi_w = hi ? c : xa;
        if (g == 0) { pa0.w4[j] = lo_w; pa0.w4[j + 2] = hi_w; }
        else        { pa1.w4[j] = lo_w; pa1.w4[j + 2] = hi_w; }
      }

    // ---- O += P @ V ----
    acc0 = __builtin_amdgcn_mfma_f32_32x32x16_bf16(pa0.v, vf[0].v, acc0, 0, 0, 0);
    acc0 = __builtin_amdgcn_mfma_f32_32x32x16_bf16(pa1.v, vf[1].v, acc0, 0, 0, 0);
    acc1 = __builtin_amdgcn_mfma_f32_32x32x16_bf16(pa0.v, vf[2].v, acc1, 0, 0, 0);
    acc1 = __builtin_amdgcn_mfma_f32_32x32x16_bf16(pa1.v, vf[3].v, acc1, 0, 0, 0);

#pragma unroll
    for (int s = 0; s < 4; ++s) kf[s] = kn[s];
  }

  // ---- epilogue: store normalized partial + (m,l) ----
  const float rinv = 1.0f / l_run;
  u16* po = pacc + (size_t)sp * 4194304 +
            (size_t)(b * NQ + qt * 128 + wid * 32) * DIMC + h * 64 + ln32;
#pragma unroll
  for (int r = 0; r < 16; ++r) {
    const int qr = (r & 3) + 8 * (r >> 2) + 4 * hi;
    const float ri = __shfl(rinv, qr);
    po[(size_t)qr * DIMC] = f2bf(acc0[r] * ri);
    po[(size_t)qr * DIMC + 32] = f2bf(acc1[r] * ri);
  }
  if (lane < 32) {
    const int mlidx = (b * NQ + qt * 128 + wid * 32 + ln32) * 16 + h;
    mlb[(sp * 2 + 0) * 65536 + mlidx] = m_run;
    mlb[(sp * 2 + 1) * 65536 + mlidx] = l_run;
  }
}

// ---------------- combine the two L-splits ----------------
__global__ void attn_combine(const u16* __restrict__ pacc, const float* __restrict__ mlb,
                             u16* __restrict__ attnb) {
  const int g = blockIdx.x * 256 + threadIdx.x;  // 524288 threads
  const int combo = g >> 3, dc = (g & 7) * 8;
  const float m0 = mlb[combo],             l0 = mlb[65536 + combo];
  const float m1 = mlb[2 * 65536 + combo], l1 = mlb[3 * 65536 + combo];
  const float m = fmaxf(m0, m1);
  const float w0 = l0 * exp2f(m0 - m), w1 = l1 * exp2f(m1 - m);
  const float rinv = 1.0f / (w0 + w1);
  const int row = combo >> 4, h = combo & 15;
  const size_t off = (size_t)row * DIMC + h * 64 + dc;
  uint4 a0 = *(const uint4*)(pacc + off);
  uint4 a1 = *(const uint4*)(pacc + 4194304 + off);
  const u16* p0 = (const u16*)&a0; const u16* p1 = (const u16*)&a1;
  union { uint4 u; u16 s[8]; } o;
#pragma unroll
  for (int j = 0; j < 8; ++j)
    o.s[j] = f2bf((w0 * bf2f(p0[j]) + w1 * bf2f(p1[j])) * rinv);
  *(uint4*)(attnb + off) = o.u;
}

extern "C" void kernel_launch(void* const* d_in, const int* in_sizes, int n_in,
                              void* d_out, int out_size, void* d_ws, size_t ws_size,
                              hipStream_t stream) {
  const float* x      = (const float*)d_in[0];
  const float* ctx    = (const float*)d_in[1];
  const float* qkv_w  = (const float*)d_in[2];
  const float* kv_y_w = (const float*)d_in[3];
  const float* proj_w = (const float*)d_in[4];
  const float* proj_b = (const float*)d_in[5];
  const float* q_norm_w = (const float*)d_in[6];
  const float* k_norm_w = (const float*)d_in[7];
  float* out = (float*)d_out;

  char* ws = (char*)d_ws;
  // region [0, 20.97MB): staging bf16 inputs, later reused for attention partials
  u16* xb    = (u16*)(ws);                // 4096*1024      (8.0 MB)
  u16* cb    = (u16*)(ws + 8388608);      // 1024*1024      (2.0 MB)
  u16* wqkv  = (u16*)(ws + 10485760);     // 3072*1024      (6.0 MB)
  u16* wkv   = (u16*)(ws + 16777216);     // 2048*1024      (4.0 MB)
  u16* wproj = (u16*)(ws + 20971520);     // 1024*1024      (2.0 MB)
  u16* qkvx  = (u16*)(ws + 23068672);     // 4096*3072      (24 MB)
  u16* kvy   = (u16*)(ws + 48234496);     // 1024*2048      (4.0 MB)
  u16* kfb   = (u16*)(ws + 52428800);     // 32*80*2048     (10 MB)
  u16* vfb   = (u16*)(ws + 62914560);     // 32*80*2048     (10 MB)
  u16* attnb = (u16*)(ws + 73400320);     // 4096*1024      (8.0 MB)
  // partials alias xb/cb/wqkv/wkv (dead by attention time)
  u16*   pacc = (u16*)(ws);               // 2 * 4096*1024 bf16 (16.78 MB)
  float* mlb  = (float*)(ws + 16777216);  // 4 * 65536 f32      (1.0 MB)

  cvt_all<<<5632, 256, 0, stream>>>(x, ctx, qkv_w, kv_y_w, proj_w, xb, cb, wqkv, wkv, wproj);

  gemm_bt<4096, 3072, 1024, true, false><<<32 * 24, 256, 0, stream>>>(xb, wqkv, qkvx, nullptr);
  gemm_bt<1024, 2048, 1024, true, false><<<8 * 16, 256, 0, stream>>>(cb, wkv, kvy, nullptr);
  reorg_kv<<<32 * 40, 256, 0, stream>>>(qkvx, kvy, k_norm_w, kfb, vfb);
  attn_fwd<<<1024, 256, 0, stream>>>(qkvx, kfb, vfb, q_norm_w, pacc, mlb);
  attn_combine<<<2048, 256, 0, stream>>>(pacc, mlb, attnb);
  gemm_bt<4096, 1024, 1024, false, true><<<32 * 8, 256, 0, stream>>>(attnb, wproj, out, proj_b);
}